// Round 8
// baseline (597.804 us; speedup 1.0000x reference)
//
#include <hip/hip_runtime.h>
#include <hip/hip_bf16.h>
#include <math.h>

// ModelParallelSoftmaxLoss: loss = mean(logsumexp(x@W^T + b) - (x@W^T+b)[lb])
// N=4096, D=512, V=100000.
// R14: B-dedup via 2-wave shared staging. R11/R12/R13 all saturate ~0.40
//      L2-line-requests/cy/CU (per-CU VMEM fill wall; matches m97/m201/
//      hipBLASLt at 0.3-0.4) -> cut request VOLUME: rh pair shared one B slab.
//      - block = 128 thr = 2 waves (rh 0/1), one ch; covers 128 rows x 64 cols.
//        Each wave stages HALF (4KB) of the shared 8KB K-step slab -> VMEM
//        per block-K-step halves vs R13. Grid 2048 = 32 mtiles x 2 ch x 32 spl.
//      - 4 shared LDS buffers (buf = ks&3): read {u}, in-flight {u+1}, write
//        {u+2} disjoint -> one raw s_barrier per K-step, no lgkm WAR fence.
//      - counted vmcnt per step {4,5,5,4} (tail {4,5,5,0}): stage packet = 4
//        loads; bias = 1 load/tile issued at ks0 AFTER the stage packet
//        (sched_barrier-pinned so queue order is exact; derivation in K_STEP).
//      - bias-LDS dropped (block LDS = 32KB -> 4 blocks/CU): per-tile per-lane
//        bias load (addr clamped to VOCAB-1; -inf select in epilogue) + 4 shfl.
//      - rh waves own disjoint rows -> no cross-wave S reduction; spart[4096][64].
//      Retained: W K-major image (prep unchanged), Aa[4][4] regs, log2e in x,
//      C=0 first-MFMA, linear lane*16 frag reads (0 conflicts), setprio,
//      XCD swizzle (resident blocks per XCD = 2 splits -> 3.2MB < 4MB L2).

#define N_ROWS 4096
#define DIM    512              // elements per row == bytes per row in fp8
#define VOCAB  100000
#define NTILES 782              // ceil(100000/128)
#define VPAD   (NTILES * 128)   // 100096
#define SPLITS 32
#define NPART  64               // 32 splits x 2 ch partials per row
#define TPS    25               // ceil(782/32)
#define XELEMS (N_ROWS * DIM)           // 2097152
#define WVALID ((size_t)VOCAB * DIM)    // 51200000
#define WBYTES ((size_t)VPAD * DIM)     // 51249152
#define TILEB  (128 * DIM)              // 65536 B: one 128-col V-tile of W image
#define PREP_BLOCKS 4096
#define PREP_F4     ((XELEMS + WBYTES) / 4)

#define LOG2E 1.44269504088896340736f

typedef __attribute__((ext_vector_type(4))) int   i32x4;
typedef __attribute__((ext_vector_type(8))) int   i32x8;
typedef __attribute__((ext_vector_type(4))) float f32x4;

#define WAITN(n) asm volatile("s_waitcnt vmcnt(" #n ")" ::: "memory")
#define SB0()    __builtin_amdgcn_sched_barrier(0)

// ---------------- helpers ----------------

__device__ __forceinline__ void gload_lds16(const char* g, char* l) {
  // async global->LDS, 16B/lane; LDS dest = wave-uniform base + lane*16;
  // global src = per-lane address.
  __builtin_amdgcn_global_load_lds(
      (const __attribute__((address_space(1))) unsigned int*)g,
      (__attribute__((address_space(3))) unsigned int*)l, 16, 0, 0);
}

__device__ __forceinline__ int pack4_fp8(float4 f, float sc) {
  int p = __builtin_amdgcn_cvt_pk_fp8_f32(f.x * sc, f.y * sc, 0, false);
  p = __builtin_amdgcn_cvt_pk_fp8_f32(f.z * sc, f.w * sc, p, true);
  return p;
}

// read one 32B fragment stored fragment-order: lo at base, hi at base+1024
__device__ __forceinline__ i32x8 frag32(const char* base) {
  i32x4 lo = *(const i32x4*)(base);
  i32x4 hi = *(const i32x4*)(base + 1024);
  return (i32x8){lo.x, lo.y, lo.z, lo.w, hi.x, hi.y, hi.z, hi.w};
}

// ---------------- prep: cvt x (row-major) + W (K-major fragment tiles) + tgt ----------------

__global__ __launch_bounds__(256) void prep_kernel(const float* __restrict__ x,
                                                   const float* __restrict__ W,
                                                   char* __restrict__ out8,
                                                   const int* __restrict__ lb,
                                                   const float* __restrict__ bias,
                                                   float* __restrict__ tgt) {
  if (blockIdx.x < PREP_BLOCKS) {
    for (size_t i4 = (size_t)blockIdx.x * 256 + threadIdx.x; i4 < (size_t)PREP_F4;
         i4 += (size_t)PREP_BLOCKS * 256) {
      const size_t f0 = i4 * 4;          // float index == out byte index
      if (f0 < (size_t)XELEMS) {
        // x pre-scaled by log2(e): GEMM yields logits*log2e -> epilogue raw exp2.
        *(int*)(out8 + f0) = pack4_fp8(*(const float4*)(x + f0), LOG2E);
      } else {
        const size_t wf = f0 - XELEMS;   // byte index in the W fp8 image
        int o = 0;
        if (wf < WVALID) o = pack4_fp8(*(const float4*)(W + wf), 32.f);
        // K-major fragment layout (bit-permutation of (v,d)):
        const unsigned v  = (unsigned)(wf >> 9);    // vocab row
        const unsigned dd = (unsigned)(wf & 511);   // byte within row
        const unsigned out = ((v >> 7) << 16)            // tile    * 65536
                           + ((dd >> 7) << 14)           // ks      * 16384
                           + (((v >> 4) & 7u) << 11)     // colgrp  * 2048
                           + (((dd >> 4) & 1u) << 10)    // half    * 1024
                           + (((dd >> 5) & 3u) << 8)     // fq      * 256
                           + ((v & 15u) << 4)            // fr      * 16
                           + (dd & 15u);                 // b
        *(int*)(out8 + XELEMS + out) = o;
      }
    }
  } else {
    // ---- tgt part: 1024 blocks x 4 waves -> 4096 rows; exact fp32 dot
    const int wv = threadIdx.x >> 6;
    const int lane = threadIdx.x & 63;
    const int row = (blockIdx.x - PREP_BLOCKS) * 4 + wv;
    const int t = lb[row];
    const float* xr = x + (size_t)row * DIM;
    const float* wr = W + (size_t)t * DIM;
    float s = 0.f;
#pragma unroll
    for (int i = 0; i < 8; ++i) s += xr[lane + i * 64] * wr[lane + i * 64];
#pragma unroll
    for (int m = 32; m; m >>= 1) s += __shfl_xor(s, m);
    if (lane == 0) tgt[row] = s + bias[t];
  }
}

// ---------------- fused MX-fp8 GEMM + sum-exp ----------------
// block: 2 waves (rh 0/1), one ch. Wave owns 64 rows (4 frags) x 64 cols
// (4 groups). K=128 MFMA, 4 K-steps/tile over D=512.
// A frag (regs, 128 VGPR): lane(fr,fq) = row fr, k-bytes fq*32..+31 per window.
// Shared B LDS: 4 buffers x 8KB, buf = ks&3; the (tile,ks,ch) slab is 8KB
// contiguous in the W image; wave rh stages bytes [rh*4K, rh*4K+4K) (4 gloads).
// Per step u: WAITN(w) [own stage(u) done] -> s_barrier [partner's half done]
// -> stage(u+2) into buf[(u+2)&3] -> {frag32, 4 MFMA} x4.
// vmcnt schedule (packet=4 loads; b=1 bias load/tile issued ks0 after packet):
//   queue per tile: ...P(4t),P(4t+1) | ks0: P(4t+2),b | ks1: P(4t+3) |
//   ks2: P(4t+4) | ks3: P(4t+5)...  waits: ks0=4 (newest4=P(u+1)),
//   ks1=5 (newest5=P(u+1)+b), ks2=5 (newest5=b? no: b,P(4t+3) newer than
//   P(4t+2): newest5={P(4t+3),b}), ks3=4 (forces b & P(4t+3); newest4=P(4t+4)).
//   Tail tile: {4,5,5,0}. WAR: buf[u+2] last read at step u-2, barrier-ordered.
// Scales: A identity (127, log2e folded into x fp8); B 2^-5 (122).

__global__ __launch_bounds__(128, 2) void lse_kernel(const char* __restrict__ xb,
                                                     const char* __restrict__ wb,
                                                     const float* __restrict__ bias,
                                                     float* __restrict__ spart) {
  __shared__ __align__(16) char ldsB[4][8192];   // 32KB shared B buffers

  // XCD swizzle: dispatch round-robins blockIdx%8 -> XCD. Encode so XCD x
  // hosts groups g=8x..8x+7 (g = split*2+ch), first-resident 128 blocks =
  // g 8x..8x+3 = 2 splits -> W working set 3.2MB < 4MB per-XCD L2.
  const int i    = blockIdx.x;
  const int xcd  = i & 7;
  const int slot = i >> 3;                 // 0..255
  const int g    = 8 * xcd + (slot >> 5);  // 0..63
  const int mtile = slot & 31;
  const int s  = g >> 1;
  const int ch = g & 1;

  const int m0 = mtile * 128;
  const int t0 = s * TPS;
  const int t1 = (t0 + TPS < NTILES) ? (t0 + TPS) : NTILES;

  const int tid  = threadIdx.x;
  const int lane = tid & 63;
  const int rh   = tid >> 6;         // wave = row-half (64 rows)
  const int fr   = lane & 15;        // frag row (A) / col (B,C)
  const int fq   = lane >> 4;        // frag quad

  // ---- load A fragments into registers (128 VGPRs): 4 row-frags x 4 ksteps ----
  i32x8 Aa[4][4];
  {
    const char* ax = xb + (size_t)(m0 + 64 * rh + fr) * DIM + fq * 32;
#pragma unroll
    for (int rf = 0; rf < 4; ++rf)
#pragma unroll
      for (int ks = 0; ks < 4; ++ks) {
        const char* p = ax + rf * (16 * DIM) + ks * 128;
        i32x4 lo = *(const i32x4*)p;
        i32x4 hi = *(const i32x4*)(p + 16);
        Aa[rf][ks] = (i32x8){lo.x, lo.y, lo.z, lo.w, hi.x, hi.y, hi.z, hi.w};
      }
  }
  // drain A loads so the counted-vmcnt queue below holds only stage packets
  WAITN(0); SB0();

  // wave stages its half of the shared (tile, ks, ch) 8KB slab: 4 x 1KB
  auto stageK = [&](const char* tileSrc, int ks, char* buf) {
    const char* src = tileSrc + ks * 16384 + ch * 8192 + rh * 4096 + lane * 16;
    char* dst = buf + rh * 4096;
#pragma unroll
    for (int j = 0; j < 4; ++j)
      gload_lds16(src + j * 1024, dst + j * 1024);
  };

  float S[4][4];
#pragma unroll
  for (int rf = 0; rf < 4; ++rf)
#pragma unroll
    for (int r = 0; r < 4; ++r) S[rf][r] = 0.f;

  f32x4 acc[4][4];   // [row-frag][col-frag]; C=0 at each tile's ks0
  float biasv = 0.f; // this tile's bias value for column (64ch + lane)

// one K-step: counted wait -> barrier -> stage(u+2) [+bias @ks0] -> 16 MFMA
#define K_STEP(ksC, FIRSTF, WAITIMM, STAGE_EXPR, BIAS_EXPR)                   \
  {                                                                           \
    WAITN(WAITIMM); SB0();                                                    \
    __builtin_amdgcn_s_barrier(); SB0();                                      \
    STAGE_EXPR;                                                               \
    SB0();            /* pin bias load AFTER the stage packet (queue order) */\
    BIAS_EXPR;                                                                \
    const char* fb_ = &ldsB[(ksC)][0] + lane * 16;                            \
    __builtin_amdgcn_s_setprio(1);                                            \
    _Pragma("unroll")                                                         \
    for (int gg_ = 0; gg_ < 4; ++gg_) {                                       \
      const i32x8 bf_ = frag32(fb_ + gg_ * 2048);                             \
      _Pragma("unroll")                                                       \
      for (int rf_ = 0; rf_ < 4; ++rf_)                                       \
        acc[rf_][gg_] = __builtin_amdgcn_mfma_scale_f32_16x16x128_f8f6f4(     \
            Aa[rf_][ksC], bf_,                                                \
            (FIRSTF) ? (f32x4){0.f, 0.f, 0.f, 0.f} : acc[rf_][gg_],           \
            0, 0, 0, 127, 0, 122);                                            \
    }                                                                         \
    __builtin_amdgcn_s_setprio(0);                                            \
  }

  auto epilogue = [&](int tt) {
    // C/D (16x16): col = tt*128 + 64ch + 16c + fr, row = m0+64rh+16rf+4fq+r.
    // bias for col 64ch+lane is in biasv (lane-indexed); redistribute by shfl.
    const int cbase = tt * 128 + 64 * ch;
    const float bvt = (cbase + lane < VOCAB) ? biasv * LOG2E : -INFINITY;
    float badd[4];
#pragma unroll
    for (int c = 0; c < 4; ++c) badd[c] = __shfl(bvt, 16 * c + fr, 64);
#pragma unroll
    for (int rf = 0; rf < 4; ++rf)
#pragma unroll
      for (int r = 0; r < 4; ++r) {
        float sum = 0.f;
#pragma unroll
        for (int c = 0; c < 4; ++c)
          sum += __builtin_amdgcn_exp2f(acc[rf][c][r] + badd[c]);
        S[rf][r] += sum;
      }
  };

  const char* wt = wb + (size_t)t0 * TILEB;

  // prologue: K-steps 0,1 of tile t0 in flight (P0,P1 = 8 loads)
  stageK(wt, 0, ldsB[0]);
  stageK(wt, 1, ldsB[1]);

  for (int tt = t0; tt < t1 - 1; ++tt, wt += TILEB) {
    const int bcol = tt * 128 + 64 * ch + lane;
    K_STEP(0, true,  4, stageK(wt, 2, ldsB[2]),
           biasv = bias[bcol < VOCAB ? bcol : (VOCAB - 1)])
    K_STEP(1, false, 5, stageK(wt, 3, ldsB[3]), (void)0)
    K_STEP(2, false, 5, stageK(wt + TILEB, 0, ldsB[0]), (void)0)
    K_STEP(3, false, 4, stageK(wt + TILEB, 1, ldsB[1]), (void)0)
    epilogue(tt);      // barrier-free tail of the tile; partner symmetric
  }

  // last tile: no next-tile stages; waits {4,5,5,0}
  {
    const int tt = t1 - 1;
    const int bcol = tt * 128 + 64 * ch + lane;
    K_STEP(0, true,  4, stageK(wt, 2, ldsB[2]),
           biasv = bias[bcol < VOCAB ? bcol : (VOCAB - 1)])
    K_STEP(1, false, 5, stageK(wt, 3, ldsB[3]), (void)0)
    K_STEP(2, false, 5, (void)0, (void)0)
    K_STEP(3, false, 0, (void)0, (void)0)
    epilogue(tt);
  }
#undef K_STEP

  // ---- reduce over the 16 fr-lanes sharing each row, write partials ----
  // rh waves own disjoint rows: no cross-wave reduction needed.
#pragma unroll
  for (int rf = 0; rf < 4; ++rf)
#pragma unroll
    for (int r = 0; r < 4; ++r) {
      float v = S[rf][r];
      v += __shfl_xor(v, 1);
      v += __shfl_xor(v, 2);
      v += __shfl_xor(v, 4);
      v += __shfl_xor(v, 8);
      if (fr == 0) {
        const int row = m0 + 64 * rh + 16 * rf + 4 * fq + r;
        spart[(size_t)row * NPART + (s * 2 + ch)] = v;
      }
    }
}

// ---------------- combine: loss = mean(log(sum_p S_part) - tgt), single block ----------------

__global__ __launch_bounds__(256) void combine_kernel(const float* __restrict__ spart,
                                                      const float* __restrict__ tgt,
                                                      float* __restrict__ out) {
  __shared__ float red[256];
  float local = 0.f;
  for (int r = threadIdx.x; r < N_ROWS; r += 256) {
    const float4* sp = (const float4*)(spart + (size_t)r * NPART);
    float st = 0.f;
#pragma unroll
    for (int i = 0; i < 16; ++i) { float4 v = sp[i]; st += (v.x + v.y) + (v.z + v.w); }
    local += __logf(st) - tgt[r];
  }
  red[threadIdx.x] = local;
  __syncthreads();
  for (int step = 128; step; step >>= 1) {
    if (threadIdx.x < step) red[threadIdx.x] += red[threadIdx.x + step];
    __syncthreads();
  }
  if (threadIdx.x == 0) out[0] = red[0] * (1.0f / (float)N_ROWS);
}

// ---------------- launch ----------------
// ws: x_fp8 [4096][512]B @0 | W_fp8 K-major tiles [782][4][8][2][64][16]B |
//     S_part [4096][64] f32 | tgt [4096] f32

extern "C" void kernel_launch(void* const* d_in, const int* in_sizes, int n_in,
                              void* d_out, int out_size, void* d_ws, size_t ws_size,
                              hipStream_t stream) {
  const float* x  = (const float*)d_in[0];
  const int*   lb = (const int*)d_in[1];
  const float* W  = (const float*)d_in[2];
  const float* b  = (const float*)d_in[3];
  float* out = (float*)d_out;

  char* ws = (char*)d_ws;
  const size_t OFF_W   = (size_t)XELEMS;          // 2097152
  const size_t OFF_SP  = OFF_W + WBYTES;          // 53346304
  const size_t OFF_TGT = OFF_SP + (size_t)N_ROWS * NPART * 4;
  char*  xb    = ws;
  char*  wb    = ws + OFF_W;
  float* spart = (float*)(ws + OFF_SP);
  float* tgt   = (float*)(ws + OFF_TGT);

  prep_kernel<<<PREP_BLOCKS + 1024, 256, 0, stream>>>(x, W, ws, lb, b, tgt);
  lse_kernel<<<2048, 128, 0, stream>>>(xb, wb, b, spart);
  combine_kernel<<<1, 256, 0, stream>>>(spart, tgt, out);
}